// Round 7
// baseline (307.236 us; speedup 1.0000x reference)
//
#include <hip/hip_runtime.h>
#include <math.h>

typedef unsigned short u16;
typedef float floatx4 __attribute__((ext_vector_type(4)));
typedef __bf16 bf16x8 __attribute__((ext_vector_type(8)));
typedef u16 u16x4 __attribute__((ext_vector_type(4)));

#define BB 2
#define SS 2048
#define HH 1024
#define NHEAD 16

// fp32 -> bf16 RNE (manual, used in cvt kernel)
__device__ __forceinline__ u16 f2bf(float f) {
  union { float f; unsigned u; } a; a.f = f;
  unsigned r = a.u + 0x7fffu + ((a.u >> 16) & 1u);
  return (u16)(r >> 16);
}

// fp32 -> bf16 via HW cvt (hot paths)
__device__ __forceinline__ u16 bfbits(float f) {
  union { __bf16 h; u16 u; } c; c.h = (__bf16)f; return c.u;
}

// two f32 -> packed 2xbf16 in one u32 (no builtin on gfx950; inline asm)
__device__ __forceinline__ unsigned cvtpk(float lo, float hi) {
  unsigned r;
  asm("v_cvt_pk_bf16_f32 %0, %1, %2" : "=v"(r) : "v"(lo), "v"(hi));
  return r;
}

// async global->LDS, 16B per lane; LDS dest must be wave-uniform base + lane*16
__device__ __forceinline__ void gload16(const u16* g, u16* l) {
  __builtin_amdgcn_global_load_lds((const __attribute__((address_space(1))) void*)g,
                                   (__attribute__((address_space(3))) void*)l, 16, 0, 0);
}

// raw workgroup barrier with compile-time memory fences on both sides
// (no implicit vmcnt(0) drain, unlike __syncthreads)
__device__ __forceinline__ void fencebar() {
  asm volatile("" ::: "memory");
  __builtin_amdgcn_s_barrier();
  asm volatile("" ::: "memory");
}

// ---------------------------------------------------------------------------
// fp32 -> bf16 conversion of pre_out (4M) + 4 weights (1M each) + mask->bias2
// bias2 = (1-mask) * -10000 * log2(e)  (exp2-domain mask bias)
// ---------------------------------------------------------------------------
__global__ __launch_bounds__(256) void cvt_all(
    const float* __restrict__ X, const float* __restrict__ Wq, const float* __restrict__ Wk,
    const float* __restrict__ Wv, const float* __restrict__ Wo, const float* __restrict__ mask,
    u16* __restrict__ Xb, u16* __restrict__ Wqb, u16* __restrict__ Wkb,
    u16* __restrict__ Wvb, u16* __restrict__ Wob, float* __restrict__ B2) {
  int i = blockIdx.x * 256 + threadIdx.x;   // each thread: 4 elements
  if (i >= (2 << 20)) {                     // mask -> bias2 (4096 floats)
    int off = i - (2 << 20);
    float4 m = ((const float4*)mask)[off];
    float4 o;
    o.x = (1.0f - m.x) * (-10000.0f * 1.44269504f);
    o.y = (1.0f - m.y) * (-10000.0f * 1.44269504f);
    o.z = (1.0f - m.z) * (-10000.0f * 1.44269504f);
    o.w = (1.0f - m.w) * (-10000.0f * 1.44269504f);
    ((float4*)B2)[off] = o;
    return;
  }
  const float* src; u16* dst; int off;
  if (i < (1 << 20)) { src = X; dst = Xb; off = i; }
  else {
    int j = i - (1 << 20);
    int m = j >> 18; off = j & ((1 << 18) - 1);
    src = (m == 0) ? Wq : (m == 1) ? Wk : (m == 2) ? Wv : Wo;
    dst = (m == 0) ? Wqb : (m == 1) ? Wkb : (m == 2) ? Wvb : Wob;
  }
  float4 v = ((const float4*)src)[off];
  u16x4 p; p.x = f2bf(v.x); p.y = f2bf(v.y); p.z = f2bf(v.z); p.w = f2bf(v.w);
  ((u16x4*)dst)[off] = p;
}

// ---------------------------------------------------------------------------
// Fused QKV GEMM: double-buffered LDS + counted vmcnt prefetch, raw barriers,
// setprio around MFMA. 128x128 tile, 4 waves, 4x4 MFMAs. XCD-swizzled grid.
// mat 0/1 -> Q,K bf16 [s][feature]; mat 2 -> V bf16 transposed [b,h,d,s].
// ---------------------------------------------------------------------------
__global__ __launch_bounds__(256) void qkv_gemm(
    const u16* __restrict__ X,
    const u16* __restrict__ Wq, const u16* __restrict__ Wk, const u16* __restrict__ Wv,
    const float* __restrict__ bq, const float* __restrict__ bk, const float* __restrict__ bv,
    u16* __restrict__ Qo, u16* __restrict__ Ko, u16* __restrict__ Vt) {
  __shared__ u16 As[2][128 * 32];
  __shared__ u16 Ws[2][128 * 32];

  const int tid = threadIdx.x;
  const int w = tid >> 6, lane = tid & 63, quad = lane >> 4, l15 = lane & 15;
  // bijective XCD swizzle: 768 blocks = 8 XCDs x 96; XCD gets 4 row panels
  const int L = blockIdx.y * 24 + blockIdx.x;
  const int wid = (L & 7) * 96 + (L >> 3);
  const int bx = wid % 24, by = wid / 24;
  const int mat = bx >> 3;
  const int col0 = (bx & 7) * 128;
  const int row0 = by * 128;
  const u16* W = (mat == 0) ? Wq : (mat == 1) ? Wk : Wv;
  const float* bias = (mat == 0) ? bq : (mat == 1) ? bk : bv;

  const int c0 = tid, c1 = tid + 256;
  const int ar0 = c0 >> 2, al0 = ((c0 & 3) ^ (ar0 & 3)) * 8;
  const int ar1 = c1 >> 2, al1 = ((c1 & 3) ^ (ar1 & 3)) * 8;
  const u16* gA0 = X + (row0 + ar0) * HH + al0;
  const u16* gA1 = X + (row0 + ar1) * HH + al1;
  const u16* gW0 = W + (col0 + ar0) * HH + al0;
  const u16* gW1 = W + (col0 + ar1) * HH + al1;

  const int wm = (w >> 1) * 64, wn = (w & 1) * 64;
  const int sw = quad ^ (l15 & 3);
  const int aoff = (wm + l15) * 32 + sw * 8;
  const int boff = (wn + l15) * 32 + sw * 8;

  auto stage = [&](int buf, int k0) {
    gload16(gA0 + k0, As[buf] + c0 * 8);
    gload16(gA1 + k0, As[buf] + c1 * 8);
    gload16(gW0 + k0, Ws[buf] + c0 * 8);
    gload16(gW1 + k0, Ws[buf] + c1 * 8);
  };

  floatx4 acc[4][4];
#pragma unroll
  for (int i = 0; i < 4; i++)
#pragma unroll
    for (int j = 0; j < 4; j++) acc[i][j] = {0.f, 0.f, 0.f, 0.f};

  stage(0, 0);   // prologue: tile 0 into buf0 (4 loads in flight)

  for (int kt = 0; kt < 32; kt++) {
    const int cur = kt & 1;
    if (kt < 31) {
      stage(cur ^ 1, (kt + 1) * 32);   // prefetch next tile (4 more loads)
      asm volatile("s_waitcnt vmcnt(4)" ::: "memory");  // oldest 4 (buf cur) done
    } else {
      asm volatile("s_waitcnt vmcnt(0)" ::: "memory");
    }
    fencebar();   // all waves' buf[cur] loads landed

    bf16x8 af[4], bfr[4];
#pragma unroll
    for (int i = 0; i < 4; i++) af[i] = *(const bf16x8*)(As[cur] + aoff + i * 512);
#pragma unroll
    for (int j = 0; j < 4; j++) bfr[j] = *(const bf16x8*)(Ws[cur] + boff + j * 512);
    __builtin_amdgcn_s_setprio(1);
#pragma unroll
    for (int i = 0; i < 4; i++)
#pragma unroll
      for (int j = 0; j < 4; j++)
        acc[i][j] = __builtin_amdgcn_mfma_f32_16x16x32_bf16(af[i], bfr[j], acc[i][j], 0, 0, 0);
    __builtin_amdgcn_s_setprio(0);

    fencebar();   // all waves done reading buf[cur] before it is re-staged
  }

  const int rb = row0 + wm + quad * 4;
  if (mat < 2) {
    u16* O = (mat == 0) ? Qo : Ko;
#pragma unroll
    for (int j = 0; j < 4; j++) {
      const int col = col0 + wn + j * 16 + l15;
      const float bj = bias[col];
#pragma unroll
      for (int i = 0; i < 4; i++) {
        const int r0 = rb + i * 16;
#pragma unroll
        for (int r = 0; r < 4; r++)
          O[(r0 + r) * HH + col] = bfbits(acc[i][j][r] + bj);
      }
    }
  } else {
#pragma unroll
    for (int j = 0; j < 4; j++) {
      const int col = col0 + wn + j * 16 + l15;
      const float bj = bias[col];
      const int h = col >> 6, d = col & 63;
#pragma unroll
      for (int i = 0; i < 4; i++) {
        const int m0 = rb + i * 16;
        const int b = m0 >> 11, s = m0 & 2047;
        u16x4 pk;
#pragma unroll
        for (int r = 0; r < 4; r++) pk[r] = bfbits(acc[i][j][r] + bj);
        *(u16x4*)(Vt + (((b * NHEAD + h) * 64 + d) * SS + s)) = pk;
      }
    }
  }
}

// ---------------------------------------------------------------------------
// Output projection GEMM: double-buffered + counted vmcnt.
// Y[4096,1024] fp32 = Ab @ Wo^T + bo; 128x64 tiles (512 blocks), 4 waves of
// 2x4 MFMAs. XCD-swizzled.
// ---------------------------------------------------------------------------
__global__ __launch_bounds__(256) void oproj_gemm(
    const u16* __restrict__ A, const u16* __restrict__ W,
    const float* __restrict__ bias, float* __restrict__ Y) {
  __shared__ u16 As[2][128 * 32];
  __shared__ u16 Ws[2][64 * 32];

  const int tid = threadIdx.x;
  const int w = tid >> 6, lane = tid & 63, quad = lane >> 4, l15 = lane & 15;
  // bijective XCD swizzle: 512 blocks = 8 XCDs x 64; XCD gets 4 row panels
  const int L = blockIdx.y * 16 + blockIdx.x;
  const int wid = (L & 7) * 64 + (L >> 3);
  const int col0 = (wid & 15) * 64;
  const int row0 = (wid >> 4) * 128;

  const int c0 = tid, c1 = tid + 256;
  const int ar0 = c0 >> 2, al0 = ((c0 & 3) ^ (ar0 & 3)) * 8;
  const int ar1 = c1 >> 2, al1 = ((c1 & 3) ^ (ar1 & 3)) * 8;
  const u16* gA0 = A + (row0 + ar0) * HH + al0;
  const u16* gA1 = A + (row0 + ar1) * HH + al1;
  const u16* gW0 = W + (col0 + ar0) * HH + al0;   // 64 rows: ar0 in 0..63

  const int wm = w * 32;
  const int sw = quad ^ (l15 & 3);
  const int aoff = (wm + l15) * 32 + sw * 8;
  const int boff = l15 * 32 + sw * 8;

  auto stage = [&](int buf, int k0) {
    gload16(gA0 + k0, As[buf] + c0 * 8);
    gload16(gA1 + k0, As[buf] + c1 * 8);
    gload16(gW0 + k0, Ws[buf] + c0 * 8);
  };

  floatx4 acc[2][4];
#pragma unroll
  for (int i = 0; i < 2; i++)
#pragma unroll
    for (int j = 0; j < 4; j++) acc[i][j] = {0.f, 0.f, 0.f, 0.f};

  stage(0, 0);

  for (int kt = 0; kt < 32; kt++) {
    const int cur = kt & 1;
    if (kt < 31) {
      stage(cur ^ 1, (kt + 1) * 32);
      asm volatile("s_waitcnt vmcnt(3)" ::: "memory");  // oldest 3 (buf cur) done
    } else {
      asm volatile("s_waitcnt vmcnt(0)" ::: "memory");
    }
    fencebar();

    bf16x8 af[2], bfr[4];
#pragma unroll
    for (int i = 0; i < 2; i++) af[i] = *(const bf16x8*)(As[cur] + aoff + i * 512);
#pragma unroll
    for (int j = 0; j < 4; j++) bfr[j] = *(const bf16x8*)(Ws[cur] + boff + j * 512);
    __builtin_amdgcn_s_setprio(1);
#pragma unroll
    for (int i = 0; i < 2; i++)
#pragma unroll
      for (int j = 0; j < 4; j++)
        acc[i][j] = __builtin_amdgcn_mfma_f32_16x16x32_bf16(af[i], bfr[j], acc[i][j], 0, 0, 0);
    __builtin_amdgcn_s_setprio(0);

    fencebar();
  }

  const int rb = row0 + wm + quad * 4;
#pragma unroll
  for (int j = 0; j < 4; j++) {
    const int col = col0 + j * 16 + l15;
    const float bj = bias[col];
#pragma unroll
    for (int i = 0; i < 2; i++) {
      const int r0 = rb + i * 16;
#pragma unroll
      for (int r = 0; r < 4; r++)
        Y[(r0 + r) * HH + col] = acc[i][j][r] + bj;
    }
  }
}

// ---------------------------------------------------------------------------
// MFMA flash attention, round-15: OCCUPANCY (3 blocks/CU, 6 waves/SIMD).
// Corrected-arithmetic diagnosis: per SIMD per iter MFMA=930cyc (25%),
// VALU=1740cyc (44%), wall=3960cyc -> ~50% idle issue slots with only
// 4 waves/SIMD to cover each wave's ds_read->S^T->softmax->PV latency chain.
// 5 scheduling variants all ~52us: scheduling can't fix missing TLP.
// Fix: LDS 66KB->48.5KB (3 K/V bufs, Q in registers) => 3 blocks/CU,
// 24 waves = 6 waves/SIMD; __launch_bounds__(512,6) caps VGPR at 85.
// In-order body (r13: S^T -> softmax-in-reg -> PV, sigma key permutation);
// 3-buf race scheme of r12 (stage kt+2 targets buf[(kt-1)%3], safe).
// Strength-reduced staging/bias pointers; rotating buffer offsets.
// ---------------------------------------------------------------------------
#define QT 128

__global__ __launch_bounds__(512, 6) void attn_mfma(
    const u16* __restrict__ Q, const u16* __restrict__ K, const u16* __restrict__ Vt,
    const float* __restrict__ B2, u16* __restrict__ O) {
  // LDS (u16 offsets):
  //   [0,12288)      K bufs 0..2 ([64][64] = 4096 u16 each)
  //   [12288,24576)  V bufs 0..2 (V^T: [d][key])
  // epilogue reuse: oS = [0,16384) (4 waves x 2048 f32 = 32KB),
  //                 lpS = [16384,16640) (128 f32)
  __shared__ u16 SMEM[24576];
  u16* const KB = SMEM;
  u16* const VB = SMEM + 12288;

  // bijective XCD swizzle: 512 blocks = 8 XCDs x 64
  const int L = blockIdx.y * 16 + blockIdx.x;
  const int wid = (L & 7) * 64 + (L >> 3);
  const int qt = wid & 15, bh = wid >> 4;
  const int b = bh >> 4, h = bh & 15;
  const int tid = threadIdx.x;
  const int w = tid >> 6, lane = tid & 63, quad = lane >> 4, l15 = lane & 15;
  const int sw = l15 & 7;
  const int qg = w & 3;          // q-row group (32 rows)
  const int khalf = w >> 2;      // key half of the 64-key tile
  const int koff = khalf * 32;

  const int qbase  = (b * SS + qt * QT) * HH + h * 64;
  const int kvbase = (b * SS) * HH + h * 64;
  const int vtbase = (b * NHEAD + h) * 64 * SS;

  // strength-reduced staging pointers (chunk swizzle pc = lc ^ (r&7))
  const int sr = tid >> 3, slc = (tid & 7) ^ (sr & 7);
  const u16* gKp = K + kvbase + sr * HH + slc * 8;
  const u16* gVp = Vt + vtbase + sr * SS + slc * 8;

  // Q fragments DIRECT global->register (no LDS staging).
  bf16x8 aQ[2][2];
#pragma unroll
  for (int mt = 0; mt < 2; mt++) {
    const u16* qr = Q + qbase + (qg * 32 + mt * 16 + l15) * HH;
    aQ[mt][0] = *(const bf16x8*)(qr + quad * 8);
    aQ[mt][1] = *(const bf16x8*)(qr + (4 + quad) * 8);
  }
  // prologue: stage tiles 0,1 into bufs 0,1 (4 loads)
  gload16(gKp, KB + tid * 8);
  gload16(gVp, VB + tid * 8);
  gload16(gKp + 64 * HH, KB + 4096 + tid * 8);
  gload16(gVp + 64, VB + 4096 + tid * 8);
  gKp += 2 * 64 * HH; gVp += 2 * 64;
  // queue: Q(4), s0(2), s1(2) -> vmcnt(2): Q + s0 done; s1 in flight
  asm volatile("s_waitcnt vmcnt(2)" ::: "memory");

  floatx4 o[2][4];
#pragma unroll
  for (int mt = 0; mt < 2; mt++)
#pragma unroll
    for (int j = 0; j < 4; j++) o[mt][j] = {0.f, 0.f, 0.f, 0.f};
  float lp[2] = {0.f, 0.f};

  const float* B2p = B2 + b * SS + koff;

  // loop-invariant fragment offsets
  const int krow0 = (koff + l15) * 64;           // K row base (kb=0)
  const int kro0 = (quad ^ sw) * 8, kro1 = ((4 + quad) ^ sw) * 8;
  const int vc0 = khalf * 4 + (quad >> 1);       // sigma key permutation
  const int vsub = (quad & 1) * 4;
  const int vo0 = (vc0 ^ sw) * 8 + vsub, vo1 = ((vc0 + 2) ^ sw) * 8 + vsub;

  int cOff = 0, nOff = 4096, sOff = 8192;        // rotating buffer offsets

  for (int kt = 0; kt < 32; kt++) {
    fencebar();   // single per-iteration rendezvous

    // bias loads FIRST so their vmcnt wait leaves the newest prefetch alive
    floatx4 bb[2];
    bb[0] = *(const floatx4*)(B2p + quad * 4);
    bb[1] = *(const floatx4*)(B2p + 16 + quad * 4);
    B2p += 64;
    asm volatile("" ::: "memory");  // pin bias-load issue before stage issue

    if (kt < 30) {
      gload16(gKp, KB + sOff + tid * 8);         // prefetch distance 2
      gload16(gVp, VB + sOff + tid * 8);
      gKp += 64 * HH; gVp += 64;
      // queue: s(kt+1)[2], bias[2], s(kt+2)[2] -> vmcnt(2) retires s(kt+1)+bias
      asm volatile("s_waitcnt vmcnt(2)" ::: "memory");
    } else {
      asm volatile("s_waitcnt vmcnt(0)" ::: "memory");
    }

    const u16* Kc = KB + cOff;
    const u16* Vc = VB + cOff;

    // S^T = K·Q^T : A = K rows of this wave's key half (2 kb blocks)
    floatx4 st[2][2];
    __builtin_amdgcn_s_setprio(1);
#pragma unroll
    for (int kb = 0; kb < 2; kb++) {
      const u16* kr = Kc + krow0 + kb * 1024;
      bf16x8 kf0 = *(const bf16x8*)(kr + kro0);
      bf16x8 kf1 = *(const bf16x8*)(kr + kro1);
#pragma unroll
      for (int mt = 0; mt < 2; mt++) {
        floatx4 z = {0.f, 0.f, 0.f, 0.f};
        z = __builtin_amdgcn_mfma_f32_16x16x32_bf16(kf0, aQ[mt][0], z, 0, 0, 0);
        st[mt][kb] = __builtin_amdgcn_mfma_f32_16x16x32_bf16(kf1, aQ[mt][1], z, 0, 0, 0);
      }
    }
    __builtin_amdgcn_s_setprio(0);

    // softmax fully in-register: exp2 -> cvt_pk -> PV A-frag (sigma trick)
    bf16x8 pa[2];
#pragma unroll
    for (int mt = 0; mt < 2; mt++) {
      float pe[2][4];
#pragma unroll
      for (int kb = 0; kb < 2; kb++)
#pragma unroll
        for (int r = 0; r < 4; r++) {
          pe[kb][r] = __builtin_amdgcn_exp2f(st[mt][kb][r] * 0.180336880f + bb[kb][r]);
          lp[mt] += pe[kb][r];
        }
      union { unsigned wd[4]; bf16x8 v; } pu;
      pu.wd[0] = cvtpk(pe[0][0], pe[0][1]);
      pu.wd[1] = cvtpk(pe[0][2], pe[0][3]);
      pu.wd[2] = cvtpk(pe[1][0], pe[1][1]);
      pu.wd[3] = cvtpk(pe[1][2], pe[1][3]);
      pa[mt] = pu.v;
    }

    // PV over this wave's 32 keys: two b64 V reads per j (2-way alias, free)
    __builtin_amdgcn_s_setprio(1);
#pragma unroll
    for (int j = 0; j < 4; j++) {
      const u16* vrow = Vc + (j * 16 + l15) * 64;
      union { u16x4 hh[2]; bf16x8 v; } vu;
      vu.hh[0] = *(const u16x4*)(vrow + vo0);
      vu.hh[1] = *(const u16x4*)(vrow + vo1);
#pragma unroll
      for (int mt = 0; mt < 2; mt++)
        o[mt][j] = __builtin_amdgcn_mfma_f32_16x16x32_bf16(pa[mt], vu.v, o[mt][j], 0, 0, 0);
    }
    __builtin_amdgcn_s_setprio(0);

    const int t = cOff; cOff = nOff; nOff = sOff; sOff = t;   // rotate bufs
  }

  fencebar();   // all waves out of the loop before o-scratch overwrites bufs

  // quad-reduce lp: lane's partial covers its quad's 8 keys for q=l15
#pragma unroll
  for (int mt = 0; mt < 2; mt++) {
    float v = lp[mt];
    v += __shfl_xor(v, 16);
    v += __shfl_xor(v, 32);
    lp[mt] = v;   // sum over this wave's 32 keys, valid in every lane
  }

  // cross-pair reduction: waves 4-7 dump partials, waves 0-3 combine + write
  float* const oS  = (float*)SMEM;             // 4 waves x [32 q][64 d] f32
  float* const lpS = (float*)(SMEM + 16384);   // 4 waves x 32 q f32
  if (w >= 4) {
    float* pb = oS + (w - 4) * 2048;
#pragma unroll
    for (int mt = 0; mt < 2; mt++) {
#pragma unroll
      for (int j = 0; j < 4; j++)
#pragma unroll
        for (int r = 0; r < 4; r++)
          pb[(mt * 16 + quad * 4 + r) * 64 + j * 16 + l15] = o[mt][j][r];
      if (quad == 0) lpS[qg * 32 + mt * 16 + l15] = lp[mt];
    }
  }
  asm volatile("s_waitcnt lgkmcnt(0)" ::: "memory");
  fencebar();

  if (w < 4) {
    const float* pb = oS + w * 2048;
    float lpt[2];
#pragma unroll
    for (int mt = 0; mt < 2; mt++)
      lpt[mt] = lp[mt] + lpS[w * 32 + mt * 16 + l15];
#pragma unroll
    for (int mt = 0; mt < 2; mt++) {
      const int orow0 = b * SS + qt * QT + qg * 32 + mt * 16 + quad * 4;
#pragma unroll
      for (int r = 0; r < 4; r++) {
        const float inv = 1.0f / __shfl(lpt[mt], quad * 4 + r);
#pragma unroll
        for (int j = 0; j < 4; j++) {
          const float val = o[mt][j][r] + pb[(mt * 16 + quad * 4 + r) * 64 + j * 16 + l15];
          O[(orow0 + r) * HH + h * 64 + j * 16 + l15] = bfbits(val * inv);
        }
      }
    }
  }
}

// ---------------------------------------------------------------------------
// out = LayerNorm(x0 + y) * w + b — wave-per-row, float4-vectorized (16B/lane),
// shuffle-only reduction (no LDS, no __syncthreads). 4 rows per 256-thr block.
// ---------------------------------------------------------------------------
__global__ __launch_bounds__(256) void add_layernorm(
    const float* __restrict__ x0, const float* __restrict__ y,
    const float* __restrict__ w, const float* __restrict__ b,
    float* __restrict__ out) {
  const int row = blockIdx.x * 4 + (threadIdx.x >> 6);
  const int l = threadIdx.x & 63;
  const float4* xr = (const float4*)(x0 + (size_t)row * HH);
  const float4* yr = (const float4*)(y + (size_t)row * HH);

  float4 v[4];
  float s = 0.f;
#pragma unroll
  for (int i = 0; i < 4; i++) {
    const float4 a = xr[l + i * 64];
    const float4 c = yr[l + i * 64];
    v[i].x = a.x + c.x; v[i].y = a.y + c.y;
    v[i].z = a.z + c.z; v[i].w = a.w + c.w;
    s += v[i].x + v[i].y + v[i].z + v[i].w;
  }
#pragma unroll
  for (int o = 1; o < 64; o <<= 1) s += __shfl_xor(s, o);
  const float mean = s * (1.0f / HH);

  float sq = 0.f;
#pragma unroll
  for (int i = 0; i < 4; i++) {
    const float dx = v[i].x - mean, dy = v[i].y - mean;
    const float dz = v[i].z - mean, dw = v[i].w - mean;
    sq += dx * dx + dy * dy + dz * dz + dw * dw;
  }
#pragma unroll
  for (int o = 1; o < 64; o <<= 1) sq += __shfl_xor(sq, o);
  const float inv = rsqrtf(sq * (1.0f / HH) + 1e-12f);

  float4* orow = (float4*)(out + (size_t)row * HH);
#pragma unroll
  for (int i = 0; i < 4; i++) {
    const float4 ww = ((const float4*)w)[l + i * 64];
    const float4 bb = ((const float4*)b)[l + i * 64];
    float4 o4;
    o4.x = ww.x * ((v[i].x - mean) * inv) + bb.x;
    o4.y = ww.y * ((v[i].y - mean) * inv) + bb.y;
    o4.z = ww.z * ((v[i].z - mean) * inv) + bb.z;
    o4.w = ww.w * ((v[i].w - mean) * inv) + bb.w;
    orow[l + i * 64] = o4;
  }
}

// ---------------------------------------------------------------------------
extern "C" void kernel_launch(void* const* d_in, const int* in_sizes, int n_in,
                              void* d_out, int out_size, void* d_ws, size_t ws_size,
                              hipStream_t stream) {
  const float* pre_out = (const float*)d_in[0];
  const float* mask    = (const float*)d_in[1];
  const float* Wq = (const float*)d_in[2];
  const float* bq = (const float*)d_in[3];
  const float* Wk = (const float*)d_in[4];
  const float* bk = (const float*)d_in[5];
  const float* Wv = (const float*)d_in[6];
  const float* bv = (const float*)d_in[7];
  const float* Wo = (const float*)d_in[8];
  const float* bo = (const float*)d_in[9];
  const float* ln_w = (const float*)d_in[10];
  const float* ln_b = (const float*)d_in[11];
  float* out = (float*)d_out;

  // workspace layout
  u16* Xb  = (u16*)d_ws;                // 4M u16
  u16* Wqb = Xb + (4 << 20);            // 1M
  u16* Wkb = Wqb + (1 << 20);
  u16* Wvb = Wkb + (1 << 20);
  u16* Wob = Wvb + (1 << 20);
  u16* Qb  = Wob + (1 << 20);           // 4M
  u16* Kb  = Qb + (4 << 20);            // 4M
  u16* Vtb = Kb + (4 << 20);            // 4M
  u16* Ab  = Vtb + (4 << 20);           // 4M
  float* Yb = (float*)(Ab + (4 << 20)); // 4M fp32
  float* B2 = Yb + (4 << 20);           // 4096 fp32 (mask bias, exp2 domain)

  cvt_all<<<8196, 256, 0, stream>>>(pre_out, Wq, Wk, Wv, Wo, mask,
                                    Xb, Wqb, Wkb, Wvb, Wob, B2);

  qkv_gemm<<<dim3(24, 32), 256, 0, stream>>>(Xb, Wqb, Wkb, Wvb, bq, bk, bv, Qb, Kb, Vtb);

  attn_mfma<<<dim3(SS / QT, BB * NHEAD), 512, 0, stream>>>(Qb, Kb, Vtb, B2, Ab);

  oproj_gemm<<<dim3(16, 32), 256, 0, stream>>>(Ab, Wob, bo, Yb);

  add_layernorm<<<BB * SS / 4, 256, 0, stream>>>(pre_out, Yb, ln_w, ln_b, out);
}

// Round 8
// 205.524 us; speedup vs baseline: 1.4949x; 1.4949x over previous
//
#include <hip/hip_runtime.h>
#include <math.h>

typedef unsigned short u16;
typedef float floatx4 __attribute__((ext_vector_type(4)));
typedef __bf16 bf16x8 __attribute__((ext_vector_type(8)));
typedef u16 u16x4 __attribute__((ext_vector_type(4)));

#define BB 2
#define SS 2048
#define HH 1024
#define NHEAD 16

// fp32 -> bf16 RNE (manual, used in cvt kernel)
__device__ __forceinline__ u16 f2bf(float f) {
  union { float f; unsigned u; } a; a.f = f;
  unsigned r = a.u + 0x7fffu + ((a.u >> 16) & 1u);
  return (u16)(r >> 16);
}

// fp32 -> bf16 via HW cvt (hot paths)
__device__ __forceinline__ u16 bfbits(float f) {
  union { __bf16 h; u16 u; } c; c.h = (__bf16)f; return c.u;
}

// two f32 -> packed 2xbf16 in one u32 (no builtin on gfx950; inline asm)
__device__ __forceinline__ unsigned cvtpk(float lo, float hi) {
  unsigned r;
  asm("v_cvt_pk_bf16_f32 %0, %1, %2" : "=v"(r) : "v"(lo), "v"(hi));
  return r;
}

// async global->LDS, 16B per lane; LDS dest must be wave-uniform base + lane*16
__device__ __forceinline__ void gload16(const u16* g, u16* l) {
  __builtin_amdgcn_global_load_lds((const __attribute__((address_space(1))) void*)g,
                                   (__attribute__((address_space(3))) void*)l, 16, 0, 0);
}

// raw workgroup barrier with compile-time memory fences on both sides
// (no implicit vmcnt(0) drain, unlike __syncthreads)
__device__ __forceinline__ void fencebar() {
  asm volatile("" ::: "memory");
  __builtin_amdgcn_s_barrier();
  asm volatile("" ::: "memory");
}

// ---------------------------------------------------------------------------
// fp32 -> bf16 conversion of pre_out (4M) + 4 weights (1M each) + mask->bias2
// bias2 = (1-mask) * -10000 * log2(e)  (exp2-domain mask bias)
// ---------------------------------------------------------------------------
__global__ __launch_bounds__(256) void cvt_all(
    const float* __restrict__ X, const float* __restrict__ Wq, const float* __restrict__ Wk,
    const float* __restrict__ Wv, const float* __restrict__ Wo, const float* __restrict__ mask,
    u16* __restrict__ Xb, u16* __restrict__ Wqb, u16* __restrict__ Wkb,
    u16* __restrict__ Wvb, u16* __restrict__ Wob, float* __restrict__ B2) {
  int i = blockIdx.x * 256 + threadIdx.x;   // each thread: 4 elements
  if (i >= (2 << 20)) {                     // mask -> bias2 (4096 floats)
    int off = i - (2 << 20);
    float4 m = ((const float4*)mask)[off];
    float4 o;
    o.x = (1.0f - m.x) * (-10000.0f * 1.44269504f);
    o.y = (1.0f - m.y) * (-10000.0f * 1.44269504f);
    o.z = (1.0f - m.z) * (-10000.0f * 1.44269504f);
    o.w = (1.0f - m.w) * (-10000.0f * 1.44269504f);
    ((float4*)B2)[off] = o;
    return;
  }
  const float* src; u16* dst; int off;
  if (i < (1 << 20)) { src = X; dst = Xb; off = i; }
  else {
    int j = i - (1 << 20);
    int m = j >> 18; off = j & ((1 << 18) - 1);
    src = (m == 0) ? Wq : (m == 1) ? Wk : (m == 2) ? Wv : Wo;
    dst = (m == 0) ? Wqb : (m == 1) ? Wkb : (m == 2) ? Wvb : Wob;
  }
  float4 v = ((const float4*)src)[off];
  u16x4 p; p.x = f2bf(v.x); p.y = f2bf(v.y); p.z = f2bf(v.z); p.w = f2bf(v.w);
  ((u16x4*)dst)[off] = p;
}

// ---------------------------------------------------------------------------
// Fused QKV GEMM: double-buffered LDS + counted vmcnt prefetch, raw barriers,
// setprio around MFMA. 128x128 tile, 4 waves, 4x4 MFMAs. XCD-swizzled grid.
// mat 0/1 -> Q,K bf16 [s][feature]; mat 2 -> V bf16 transposed [b,h,d,s].
// ---------------------------------------------------------------------------
__global__ __launch_bounds__(256) void qkv_gemm(
    const u16* __restrict__ X,
    const u16* __restrict__ Wq, const u16* __restrict__ Wk, const u16* __restrict__ Wv,
    const float* __restrict__ bq, const float* __restrict__ bk, const float* __restrict__ bv,
    u16* __restrict__ Qo, u16* __restrict__ Ko, u16* __restrict__ Vt) {
  __shared__ u16 As[2][128 * 32];
  __shared__ u16 Ws[2][128 * 32];

  const int tid = threadIdx.x;
  const int w = tid >> 6, lane = tid & 63, quad = lane >> 4, l15 = lane & 15;
  // bijective XCD swizzle: 768 blocks = 8 XCDs x 96; XCD gets 4 row panels
  const int L = blockIdx.y * 24 + blockIdx.x;
  const int wid = (L & 7) * 96 + (L >> 3);
  const int bx = wid % 24, by = wid / 24;
  const int mat = bx >> 3;
  const int col0 = (bx & 7) * 128;
  const int row0 = by * 128;
  const u16* W = (mat == 0) ? Wq : (mat == 1) ? Wk : Wv;
  const float* bias = (mat == 0) ? bq : (mat == 1) ? bk : bv;

  const int c0 = tid, c1 = tid + 256;
  const int ar0 = c0 >> 2, al0 = ((c0 & 3) ^ (ar0 & 3)) * 8;
  const int ar1 = c1 >> 2, al1 = ((c1 & 3) ^ (ar1 & 3)) * 8;
  const u16* gA0 = X + (row0 + ar0) * HH + al0;
  const u16* gA1 = X + (row0 + ar1) * HH + al1;
  const u16* gW0 = W + (col0 + ar0) * HH + al0;
  const u16* gW1 = W + (col0 + ar1) * HH + al1;

  const int wm = (w >> 1) * 64, wn = (w & 1) * 64;
  const int sw = quad ^ (l15 & 3);
  const int aoff = (wm + l15) * 32 + sw * 8;
  const int boff = (wn + l15) * 32 + sw * 8;

  auto stage = [&](int buf, int k0) {
    gload16(gA0 + k0, As[buf] + c0 * 8);
    gload16(gA1 + k0, As[buf] + c1 * 8);
    gload16(gW0 + k0, Ws[buf] + c0 * 8);
    gload16(gW1 + k0, Ws[buf] + c1 * 8);
  };

  floatx4 acc[4][4];
#pragma unroll
  for (int i = 0; i < 4; i++)
#pragma unroll
    for (int j = 0; j < 4; j++) acc[i][j] = {0.f, 0.f, 0.f, 0.f};

  stage(0, 0);   // prologue: tile 0 into buf0 (4 loads in flight)

  for (int kt = 0; kt < 32; kt++) {
    const int cur = kt & 1;
    if (kt < 31) {
      stage(cur ^ 1, (kt + 1) * 32);   // prefetch next tile (4 more loads)
      asm volatile("s_waitcnt vmcnt(4)" ::: "memory");  // oldest 4 (buf cur) done
    } else {
      asm volatile("s_waitcnt vmcnt(0)" ::: "memory");
    }
    fencebar();   // all waves' buf[cur] loads landed

    bf16x8 af[4], bfr[4];
#pragma unroll
    for (int i = 0; i < 4; i++) af[i] = *(const bf16x8*)(As[cur] + aoff + i * 512);
#pragma unroll
    for (int j = 0; j < 4; j++) bfr[j] = *(const bf16x8*)(Ws[cur] + boff + j * 512);
    __builtin_amdgcn_s_setprio(1);
#pragma unroll
    for (int i = 0; i < 4; i++)
#pragma unroll
      for (int j = 0; j < 4; j++)
        acc[i][j] = __builtin_amdgcn_mfma_f32_16x16x32_bf16(af[i], bfr[j], acc[i][j], 0, 0, 0);
    __builtin_amdgcn_s_setprio(0);

    fencebar();   // all waves done reading buf[cur] before it is re-staged
  }

  const int rb = row0 + wm + quad * 4;
  if (mat < 2) {
    u16* O = (mat == 0) ? Qo : Ko;
#pragma unroll
    for (int j = 0; j < 4; j++) {
      const int col = col0 + wn + j * 16 + l15;
      const float bj = bias[col];
#pragma unroll
      for (int i = 0; i < 4; i++) {
        const int r0 = rb + i * 16;
#pragma unroll
        for (int r = 0; r < 4; r++)
          O[(r0 + r) * HH + col] = bfbits(acc[i][j][r] + bj);
      }
    }
  } else {
#pragma unroll
    for (int j = 0; j < 4; j++) {
      const int col = col0 + wn + j * 16 + l15;
      const float bj = bias[col];
      const int h = col >> 6, d = col & 63;
#pragma unroll
      for (int i = 0; i < 4; i++) {
        const int m0 = rb + i * 16;
        const int b = m0 >> 11, s = m0 & 2047;
        u16x4 pk;
#pragma unroll
        for (int r = 0; r < 4; r++) pk[r] = bfbits(acc[i][j][r] + bj);
        *(u16x4*)(Vt + (((b * NHEAD + h) * 64 + d) * SS + s)) = pk;
      }
    }
  }
}

// ---------------------------------------------------------------------------
// Output projection GEMM: double-buffered + counted vmcnt.
// Y[4096,1024] fp32 = Ab @ Wo^T + bo; 128x64 tiles (512 blocks), 4 waves of
// 2x4 MFMAs. XCD-swizzled.
// ---------------------------------------------------------------------------
__global__ __launch_bounds__(256) void oproj_gemm(
    const u16* __restrict__ A, const u16* __restrict__ W,
    const float* __restrict__ bias, float* __restrict__ Y) {
  __shared__ u16 As[2][128 * 32];
  __shared__ u16 Ws[2][64 * 32];

  const int tid = threadIdx.x;
  const int w = tid >> 6, lane = tid & 63, quad = lane >> 4, l15 = lane & 15;
  // bijective XCD swizzle: 512 blocks = 8 XCDs x 64; XCD gets 4 row panels
  const int L = blockIdx.y * 16 + blockIdx.x;
  const int wid = (L & 7) * 64 + (L >> 3);
  const int col0 = (wid & 15) * 64;
  const int row0 = (wid >> 4) * 128;

  const int c0 = tid, c1 = tid + 256;
  const int ar0 = c0 >> 2, al0 = ((c0 & 3) ^ (ar0 & 3)) * 8;
  const int ar1 = c1 >> 2, al1 = ((c1 & 3) ^ (ar1 & 3)) * 8;
  const u16* gA0 = A + (row0 + ar0) * HH + al0;
  const u16* gA1 = A + (row0 + ar1) * HH + al1;
  const u16* gW0 = W + (col0 + ar0) * HH + al0;   // 64 rows: ar0 in 0..63

  const int wm = w * 32;
  const int sw = quad ^ (l15 & 3);
  const int aoff = (wm + l15) * 32 + sw * 8;
  const int boff = l15 * 32 + sw * 8;

  auto stage = [&](int buf, int k0) {
    gload16(gA0 + k0, As[buf] + c0 * 8);
    gload16(gA1 + k0, As[buf] + c1 * 8);
    gload16(gW0 + k0, Ws[buf] + c0 * 8);
  };

  floatx4 acc[2][4];
#pragma unroll
  for (int i = 0; i < 2; i++)
#pragma unroll
    for (int j = 0; j < 4; j++) acc[i][j] = {0.f, 0.f, 0.f, 0.f};

  stage(0, 0);

  for (int kt = 0; kt < 32; kt++) {
    const int cur = kt & 1;
    if (kt < 31) {
      stage(cur ^ 1, (kt + 1) * 32);
      asm volatile("s_waitcnt vmcnt(3)" ::: "memory");  // oldest 3 (buf cur) done
    } else {
      asm volatile("s_waitcnt vmcnt(0)" ::: "memory");
    }
    fencebar();

    bf16x8 af[2], bfr[4];
#pragma unroll
    for (int i = 0; i < 2; i++) af[i] = *(const bf16x8*)(As[cur] + aoff + i * 512);
#pragma unroll
    for (int j = 0; j < 4; j++) bfr[j] = *(const bf16x8*)(Ws[cur] + boff + j * 512);
    __builtin_amdgcn_s_setprio(1);
#pragma unroll
    for (int i = 0; i < 2; i++)
#pragma unroll
      for (int j = 0; j < 4; j++)
        acc[i][j] = __builtin_amdgcn_mfma_f32_16x16x32_bf16(af[i], bfr[j], acc[i][j], 0, 0, 0);
    __builtin_amdgcn_s_setprio(0);

    fencebar();
  }

  const int rb = row0 + wm + quad * 4;
#pragma unroll
  for (int j = 0; j < 4; j++) {
    const int col = col0 + j * 16 + l15;
    const float bj = bias[col];
#pragma unroll
    for (int i = 0; i < 2; i++) {
      const int r0 = rb + i * 16;
#pragma unroll
      for (int r = 0; r < 4; r++)
        Y[(r0 + r) * HH + col] = acc[i][j][r] + bj;
    }
  }
}

// ---------------------------------------------------------------------------
// MFMA flash attention, round-16: occupancy via LDS ONLY (spill fix).
// r15's __launch_bounds__(512,6) forced VGPR cap -> 40 and the accumulators
// spilled to scratch (WRITE_SIZE 8KB -> 258MB, 3x slowdown). Single-variable
// retry: identical kernel, __launch_bounds__(512,4) (VGPR cap 128, natural
// allocation ~52-64). Occupancy limiter is then LDS: 49152B x 3 = 144KB
// <= 160KB -> 3 blocks/CU = 6 waves/SIMD, no spill (needs natural VGPR<=85).
// Body: r13 in-order (S^T -> softmax-in-reg -> PV, sigma key permutation),
// 3 K/V bufs, Q in registers, single barrier/iter, counted vmcnt, key-split
// wave pairs, setprio, bijective XCD swizzle.
// ---------------------------------------------------------------------------
#define QT 128

__global__ __launch_bounds__(512, 4) void attn_mfma(
    const u16* __restrict__ Q, const u16* __restrict__ K, const u16* __restrict__ Vt,
    const float* __restrict__ B2, u16* __restrict__ O) {
  // LDS (u16 offsets):
  //   [0,12288)      K bufs 0..2 ([64][64] = 4096 u16 each)
  //   [12288,24576)  V bufs 0..2 (V^T: [d][key])
  // epilogue reuse: oS = [0,16384) (4 waves x 2048 f32 = 32KB),
  //                 lpS = [16384,16640) (128 f32)
  __shared__ u16 SMEM[24576];
  u16* const KB = SMEM;
  u16* const VB = SMEM + 12288;

  // bijective XCD swizzle: 512 blocks = 8 XCDs x 64
  const int L = blockIdx.y * 16 + blockIdx.x;
  const int wid = (L & 7) * 64 + (L >> 3);
  const int qt = wid & 15, bh = wid >> 4;
  const int b = bh >> 4, h = bh & 15;
  const int tid = threadIdx.x;
  const int w = tid >> 6, lane = tid & 63, quad = lane >> 4, l15 = lane & 15;
  const int sw = l15 & 7;
  const int qg = w & 3;          // q-row group (32 rows)
  const int khalf = w >> 2;      // key half of the 64-key tile
  const int koff = khalf * 32;

  const int qbase  = (b * SS + qt * QT) * HH + h * 64;
  const int kvbase = (b * SS) * HH + h * 64;
  const int vtbase = (b * NHEAD + h) * 64 * SS;

  // strength-reduced staging pointers (chunk swizzle pc = lc ^ (r&7))
  const int sr = tid >> 3, slc = (tid & 7) ^ (sr & 7);
  const u16* gKp = K + kvbase + sr * HH + slc * 8;
  const u16* gVp = Vt + vtbase + sr * SS + slc * 8;

  // Q fragments DIRECT global->register (no LDS staging).
  bf16x8 aQ[2][2];
#pragma unroll
  for (int mt = 0; mt < 2; mt++) {
    const u16* qr = Q + qbase + (qg * 32 + mt * 16 + l15) * HH;
    aQ[mt][0] = *(const bf16x8*)(qr + quad * 8);
    aQ[mt][1] = *(const bf16x8*)(qr + (4 + quad) * 8);
  }
  // prologue: stage tiles 0,1 into bufs 0,1 (4 loads)
  gload16(gKp, KB + tid * 8);
  gload16(gVp, VB + tid * 8);
  gload16(gKp + 64 * HH, KB + 4096 + tid * 8);
  gload16(gVp + 64, VB + 4096 + tid * 8);
  gKp += 2 * 64 * HH; gVp += 2 * 64;
  // queue: Q(4), s0(2), s1(2) -> vmcnt(2): Q + s0 done; s1 in flight
  asm volatile("s_waitcnt vmcnt(2)" ::: "memory");

  floatx4 o[2][4];
#pragma unroll
  for (int mt = 0; mt < 2; mt++)
#pragma unroll
    for (int j = 0; j < 4; j++) o[mt][j] = {0.f, 0.f, 0.f, 0.f};
  float lp[2] = {0.f, 0.f};

  const float* B2p = B2 + b * SS + koff;

  // loop-invariant fragment offsets
  const int krow0 = (koff + l15) * 64;           // K row base (kb=0)
  const int kro0 = (quad ^ sw) * 8, kro1 = ((4 + quad) ^ sw) * 8;
  const int vc0 = khalf * 4 + (quad >> 1);       // sigma key permutation
  const int vsub = (quad & 1) * 4;
  const int vo0 = (vc0 ^ sw) * 8 + vsub, vo1 = ((vc0 + 2) ^ sw) * 8 + vsub;

  int cOff = 0, nOff = 4096, sOff = 8192;        // rotating buffer offsets

  for (int kt = 0; kt < 32; kt++) {
    fencebar();   // single per-iteration rendezvous

    // bias loads FIRST so their vmcnt wait leaves the newest prefetch alive
    floatx4 bb[2];
    bb[0] = *(const floatx4*)(B2p + quad * 4);
    bb[1] = *(const floatx4*)(B2p + 16 + quad * 4);
    B2p += 64;
    asm volatile("" ::: "memory");  // pin bias-load issue before stage issue

    if (kt < 30) {
      gload16(gKp, KB + sOff + tid * 8);         // prefetch distance 2
      gload16(gVp, VB + sOff + tid * 8);
      gKp += 64 * HH; gVp += 64;
      // queue: s(kt+1)[2], bias[2], s(kt+2)[2] -> vmcnt(2) retires s(kt+1)+bias
      asm volatile("s_waitcnt vmcnt(2)" ::: "memory");
    } else {
      asm volatile("s_waitcnt vmcnt(0)" ::: "memory");
    }

    const u16* Kc = KB + cOff;
    const u16* Vc = VB + cOff;

    // S^T = K·Q^T : A = K rows of this wave's key half (2 kb blocks)
    floatx4 st[2][2];
    __builtin_amdgcn_s_setprio(1);
#pragma unroll
    for (int kb = 0; kb < 2; kb++) {
      const u16* kr = Kc + krow0 + kb * 1024;
      bf16x8 kf0 = *(const bf16x8*)(kr + kro0);
      bf16x8 kf1 = *(const bf16x8*)(kr + kro1);
#pragma unroll
      for (int mt = 0; mt < 2; mt++) {
        floatx4 z = {0.f, 0.f, 0.f, 0.f};
        z = __builtin_amdgcn_mfma_f32_16x16x32_bf16(kf0, aQ[mt][0], z, 0, 0, 0);
        st[mt][kb] = __builtin_amdgcn_mfma_f32_16x16x32_bf16(kf1, aQ[mt][1], z, 0, 0, 0);
      }
    }
    __builtin_amdgcn_s_setprio(0);

    // softmax fully in-register: exp2 -> cvt_pk -> PV A-frag (sigma trick)
    bf16x8 pa[2];
#pragma unroll
    for (int mt = 0; mt < 2; mt++) {
      float pe[2][4];
#pragma unroll
      for (int kb = 0; kb < 2; kb++)
#pragma unroll
        for (int r = 0; r < 4; r++) {
          pe[kb][r] = __builtin_amdgcn_exp2f(st[mt][kb][r] * 0.180336880f + bb[kb][r]);
          lp[mt] += pe[kb][r];
        }
      union { unsigned wd[4]; bf16x8 v; } pu;
      pu.wd[0] = cvtpk(pe[0][0], pe[0][1]);
      pu.wd[1] = cvtpk(pe[0][2], pe[0][3]);
      pu.wd[2] = cvtpk(pe[1][0], pe[1][1]);
      pu.wd[3] = cvtpk(pe[1][2], pe[1][3]);
      pa[mt] = pu.v;
    }

    // PV over this wave's 32 keys: two b64 V reads per j (2-way alias, free)
    __builtin_amdgcn_s_setprio(1);
#pragma unroll
    for (int j = 0; j < 4; j++) {
      const u16* vrow = Vc + (j * 16 + l15) * 64;
      union { u16x4 hh[2]; bf16x8 v; } vu;
      vu.hh[0] = *(const u16x4*)(vrow + vo0);
      vu.hh[1] = *(const u16x4*)(vrow + vo1);
#pragma unroll
      for (int mt = 0; mt < 2; mt++)
        o[mt][j] = __builtin_amdgcn_mfma_f32_16x16x32_bf16(pa[mt], vu.v, o[mt][j], 0, 0, 0);
    }
    __builtin_amdgcn_s_setprio(0);

    const int t = cOff; cOff = nOff; nOff = sOff; sOff = t;   // rotate bufs
  }

  fencebar();   // all waves out of the loop before o-scratch overwrites bufs

  // quad-reduce lp: lane's partial covers its quad's 8 keys for q=l15
#pragma unroll
  for (int mt = 0; mt < 2; mt++) {
    float v = lp[mt];
    v += __shfl_xor(v, 16);
    v += __shfl_xor(v, 32);
    lp[mt] = v;   // sum over this wave's 32 keys, valid in every lane
  }

  // cross-pair reduction: waves 4-7 dump partials, waves 0-3 combine + write
  float* const oS  = (float*)SMEM;             // 4 waves x [32 q][64 d] f32
  float* const lpS = (float*)(SMEM + 16384);   // 4 waves x 32 q f32
  if (w >= 4) {
    float* pb = oS + (w - 4) * 2048;
#pragma unroll
    for (int mt = 0; mt < 2; mt++) {
#pragma unroll
      for (int j = 0; j < 4; j++)
#pragma unroll
        for (int r = 0; r < 4; r++)
          pb[(mt * 16 + quad * 4 + r) * 64 + j * 16 + l15] = o[mt][j][r];
      if (quad == 0) lpS[qg * 32 + mt * 16 + l15] = lp[mt];
    }
  }
  asm volatile("s_waitcnt lgkmcnt(0)" ::: "memory");
  fencebar();

  if (w < 4) {
    const float* pb = oS + w * 2048;
    float lpt[2];
#pragma unroll
    for (int mt = 0; mt < 2; mt++)
      lpt[mt] = lp[mt] + lpS[w * 32 + mt * 16 + l15];
#pragma unroll
    for (int mt = 0; mt < 2; mt++) {
      const int orow0 = b * SS + qt * QT + qg * 32 + mt * 16 + quad * 4;
#pragma unroll
      for (int r = 0; r < 4; r++) {
        const float inv = 1.0f / __shfl(lpt[mt], quad * 4 + r);
#pragma unroll
        for (int j = 0; j < 4; j++) {
          const float val = o[mt][j][r] + pb[(mt * 16 + quad * 4 + r) * 64 + j * 16 + l15];
          O[(orow0 + r) * HH + h * 64 + j * 16 + l15] = bfbits(val * inv);
        }
      }
    }
  }
}

// ---------------------------------------------------------------------------
// out = LayerNorm(x0 + y) * w + b — wave-per-row, float4-vectorized (16B/lane),
// shuffle-only reduction (no LDS, no __syncthreads). 4 rows per 256-thr block.
// ---------------------------------------------------------------------------
__global__ __launch_bounds__(256) void add_layernorm(
    const float* __restrict__ x0, const float* __restrict__ y,
    const float* __restrict__ w, const float* __restrict__ b,
    float* __restrict__ out) {
  const int row = blockIdx.x * 4 + (threadIdx.x >> 6);
  const int l = threadIdx.x & 63;
  const float4* xr = (const float4*)(x0 + (size_t)row * HH);
  const float4* yr = (const float4*)(y + (size_t)row * HH);

  float4 v[4];
  float s = 0.f;
#pragma unroll
  for (int i = 0; i < 4; i++) {
    const float4 a = xr[l + i * 64];
    const float4 c = yr[l + i * 64];
    v[i].x = a.x + c.x; v[i].y = a.y + c.y;
    v[i].z = a.z + c.z; v[i].w = a.w + c.w;
    s += v[i].x + v[i].y + v[i].z + v[i].w;
  }
#pragma unroll
  for (int o = 1; o < 64; o <<= 1) s += __shfl_xor(s, o);
  const float mean = s * (1.0f / HH);

  float sq = 0.f;
#pragma unroll
  for (int i = 0; i < 4; i++) {
    const float dx = v[i].x - mean, dy = v[i].y - mean;
    const float dz = v[i].z - mean, dw = v[i].w - mean;
    sq += dx * dx + dy * dy + dz * dz + dw * dw;
  }
#pragma unroll
  for (int o = 1; o < 64; o <<= 1) sq += __shfl_xor(sq, o);
  const float inv = rsqrtf(sq * (1.0f / HH) + 1e-12f);

  float4* orow = (float4*)(out + (size_t)row * HH);
#pragma unroll
  for (int i = 0; i < 4; i++) {
    const float4 ww = ((const float4*)w)[l + i * 64];
    const float4 bb = ((const float4*)b)[l + i * 64];
    float4 o4;
    o4.x = ww.x * ((v[i].x - mean) * inv) + bb.x;
    o4.y = ww.y * ((v[i].y - mean) * inv) + bb.y;
    o4.z = ww.z * ((v[i].z - mean) * inv) + bb.z;
    o4.w = ww.w * ((v[i].w - mean) * inv) + bb.w;
    orow[l + i * 64] = o4;
  }
}

// ---------------------------------------------------------------------------
extern "C" void kernel_launch(void* const* d_in, const int* in_sizes, int n_in,
                              void* d_out, int out_size, void* d_ws, size_t ws_size,
                              hipStream_t stream) {
  const float* pre_out = (const float*)d_in[0];
  const float* mask    = (const float*)d_in[1];
  const float* Wq = (const float*)d_in[2];
  const float* bq = (const float*)d_in[3];
  const float* Wk = (const float*)d_in[4];
  const float* bk = (const float*)d_in[5];
  const float* Wv = (const float*)d_in[6];
  const float* bv = (const float*)d_in[7];
  const float* Wo = (const float*)d_in[8];
  const float* bo = (const float*)d_in[9];
  const float* ln_w = (const float*)d_in[10];
  const float* ln_b = (const float*)d_in[11];
  float* out = (float*)d_out;

  // workspace layout
  u16* Xb  = (u16*)d_ws;                // 4M u16
  u16* Wqb = Xb + (4 << 20);            // 1M
  u16* Wkb = Wqb + (1 << 20);
  u16* Wvb = Wkb + (1 << 20);
  u16* Wob = Wvb + (1 << 20);
  u16* Qb  = Wob + (1 << 20);           // 4M
  u16* Kb  = Qb + (4 << 20);            // 4M
  u16* Vtb = Kb + (4 << 20);            // 4M
  u16* Ab  = Vtb + (4 << 20);           // 4M
  float* Yb = (float*)(Ab + (4 << 20)); // 4M fp32
  float* B2 = Yb + (4 << 20);           // 4096 fp32 (mask bias, exp2 domain)

  cvt_all<<<8196, 256, 0, stream>>>(pre_out, Wq, Wk, Wv, Wo, mask,
                                    Xb, Wqb, Wkb, Wvb, Wob, B2);

  qkv_gemm<<<dim3(24, 32), 256, 0, stream>>>(Xb, Wqb, Wkb, Wvb, bq, bk, bv, Qb, Kb, Vtb);

  attn_mfma<<<dim3(SS / QT, BB * NHEAD), 512, 0, stream>>>(Qb, Kb, Vtb, B2, Ab);

  oproj_gemm<<<dim3(16, 32), 256, 0, stream>>>(Ab, Wob, bo, Yb);

  add_layernorm<<<BB * SS / 4, 256, 0, stream>>>(pre_out, Yb, ln_w, ln_b, out);
}